// Round 1
// baseline (187.285 us; speedup 1.0000x reference)
//
#include <hip/hip_runtime.h>

#define IN_H 512
#define IN_W 512

// One block = 8-row x 256-col strip (32 tiles), all 3 channels.
// Grid: 32 batches * 64 strip-rows * 2 strip-cols = 4096 blocks.
//
// LDS (30.5 KB -> 5 blocks/CU, was 4):
//  Ys  @     0 : 32 tiles x 68 f64 (tile-major, pad 4)   = 17408
//      Vt aliased into last 272 B of each tile's Ys region (wave-private:
//      after the block barrier, tile q8's Ys rows are only ever read by
//      wave q8>>3 during the c=0 fold, which completes -- in DS program
//      order -- before that wave's Vt writes land there).
//  CbS @ 17408 : 32 tiles x 18 f64 (4x4 subsampled +2)   =  4608
//  CrS @ 22016 : 32 tiles x 18 f64                       =  4608
//  qt  @ 26624 : 3 ch x 8 cols x 9 double2 {1/q, q}      =  3456
//  Dd  @ 30080 : 8x4 f64 half-DCT table                  =   256
//  Dh  @ 30336 : 8x4 f32 half-DCT table                  =   128
//
// R5: identical arithmetic to R4 (bit-for-bit); pure LDS-layout change to
// raise occupancy 16 -> 20 waves/CU (latency-bound kernel: VALU/HBM/LDS all
// at ~35-40% with ~24us floors each vs 65us actual).

__global__ __launch_bounds__(256, 5) void jpeg_kernel(
    const float* __restrict__ in, const float* __restrict__ qz,
    const float* __restrict__ dmtx, float* __restrict__ out)
{
    __shared__ __align__(16) unsigned char smem[30464];
    double*  Ys  = (double*) (smem);
    double*  CbS = (double*) (smem + 17408);
    double*  CrS = (double*) (smem + 22016);
    double2* qt  = (double2*)(smem + 26624);
    double*  Dd  = (double*) (smem + 30080);
    float*   Dh  = (float*)  (smem + 30336);

    const int t   = threadIdx.x;
    const int blk = blockIdx.x;
    const int b   = blk >> 7;
    const int rr  = blk & 127;
    const int row0 = (rr >> 1) << 3;
    const int col0 = (rr & 1) << 8;
    const int chs = IN_H * IN_W;

    // ---- P0: tables ----
    if (t < 192) {
        const int c = t >> 6, i = (t >> 3) & 7, l = t & 7;
        double v  = (double)qz[t];
        double t1 = rint((rint(v * 255.0) * 50.0 + 50.0) / 100.0); // true div: .5 ties
        double q  = fmin(fmax(t1, 1.0), 255.0);
        qt[(c * 8 + l) * 9 + i] = make_double2(1.0 / q, q);
    }
    if (t < 32) {
        float dv = dmtx[(t >> 2) * 8 + (t & 3)];   // half table D[i][0..3]
        Dd[t] = (double)dv;
        Dh[t] = dv;
    }

    // ---- P1: load, RGB->YCbCr (f64), subsample, stage (tile-major) ----
    const int s  = t >> 6;   // row-pair 0..3
    const int c4 = t & 63;   // 4-col group
    {
        const int base = ((b * 3) * IN_H + row0 + 2 * s) * IN_W + col0 + 4 * c4;
        float4 ra = *(const float4*)(in + base);
        float4 rb = *(const float4*)(in + base + IN_W);
        float4 ga = *(const float4*)(in + base + chs);
        float4 gb = *(const float4*)(in + base + chs + IN_W);
        float4 ba = *(const float4*)(in + base + 2 * chs);
        float4 bb = *(const float4*)(in + base + 2 * chs + IN_W);

        float rA[2][4] = {{ra.x,ra.y,ra.z,ra.w},{rb.x,rb.y,rb.z,rb.w}};
        float gA[2][4] = {{ga.x,ga.y,ga.z,ga.w},{gb.x,gb.y,gb.z,gb.w}};
        float bA[2][4] = {{ba.x,ba.y,ba.z,ba.w},{bb.x,bb.y,bb.z,bb.w}};

        double yv[2][4], cbv[2][4], crv[2][4];
        #pragma unroll
        for (int p = 0; p < 2; ++p) {
            #pragma unroll
            for (int k = 0; k < 4; ++k) {
                double R = 255.0 * (double)rA[p][k];
                double G = 255.0 * (double)gA[p][k];
                double B = 255.0 * (double)bA[p][k];
                double y  =  0.299*R + 0.587*G + 0.114*B;
                double cb = -0.168735892*R - 0.331264108*G + 0.5*B + 128.0;
                double cr =  0.5*R - 0.418687589*G - 0.081312411*B + 128.0;
                yv[p][k]  = fmin(fmax(y , 0.0), 255.0) - 128.0;
                cbv[p][k] = fmin(fmax(cb, 0.0), 255.0);
                crv[p][k] = fmin(fmax(cr, 0.0), 255.0);
            }
        }
        const int tile = c4 >> 1, half = c4 & 1;
        #pragma unroll
        for (int p = 0; p < 2; ++p) {
            double* yp = &Ys[tile * 68 + (2*s + p) * 8 + 4 * half];
            *(double2*)(yp)     = make_double2(yv[p][0], yv[p][1]);
            *(double2*)(yp + 2) = make_double2(yv[p][2], yv[p][3]);
        }
        double m0 = (cbv[0][0]+cbv[0][1]+cbv[1][0]+cbv[1][1])*0.25 - 128.0;
        double m1 = (cbv[0][2]+cbv[0][3]+cbv[1][2]+cbv[1][3])*0.25 - 128.0;
        *(double2*)&CbS[tile * 18 + s * 4 + 2 * half] = make_double2(m0, m1);
        double n0 = (crv[0][0]+crv[0][1]+crv[1][0]+crv[1][1])*0.25 - 128.0;
        double n1 = (crv[0][2]+crv[0][3]+crv[1][2]+crv[1][3])*0.25 - 128.0;
        *(double2*)&CrS[tile * 18 + s * 4 + 2 * half] = make_double2(n0, n1);
    }
    __syncthreads();   // the ONLY block barrier

    // ---- per-thread constants ----
    const int q8 = t >> 3;     // tile 0..31
    const int l  = t & 7;      // DCT column (F) / pixel row (I) this thread owns
    double dl0, dl1, dl2, dl3;  // D[l][0..3]
    {
        double2 dA = *(const double2*)&Dd[l * 4];
        double2 dB = *(const double2*)&Dd[l * 4 + 2];
        dl0 = dA.x; dl1 = dA.y; dl2 = dB.x; dl3 = dB.y;
    }
    const double sgn  = (l & 1) ? -1.0 : 1.0;
    const double dl01 = dl0 + dl1, dl23 = dl2 + dl3;
    // f32 half-table in registers (reused by both IDCT folds, all channels)
    const float4* dh4p = (const float4*)Dh;
    float4 d0 = dh4p[0], d1 = dh4p[1], d2 = dh4p[2], d3 = dh4p[3];
    float4 d4 = dh4p[4], d5 = dh4p[5], d6 = dh4p[6], d7 = dh4p[7];

    float acc[3][8];
    // wave-private tile patch, aliased into the tail 272 B of this tile's
    // Ys region (dead after this wave's own c=0 fold reads)
    float* vtw = (float*)(smem + q8 * 544 + 272);

    #pragma unroll
    for (int c = 0; c < 3; ++c) {
        // ---- F: row DCT streamed in fold order -> e2/o2 -> col DCT + quant ----
        double e2[4], o2[4];
        if (c == 0) {
            const double* base = &Ys[q8 * 68];
            #pragma unroll
            for (int m = 0; m < 4; ++m) {
                double tp[2];
                #pragma unroll
                for (int h = 0; h < 2; ++h) {
                    const double* p = base + (h ? (7 - m) : m) * 8;
                    double2 a0 = *(const double2*)(p);
                    double2 a1 = *(const double2*)(p + 2);
                    double2 a2 = *(const double2*)(p + 4);
                    double2 a3 = *(const double2*)(p + 6);
                    double v0 = fma(sgn, a3.y, a0.x);
                    double v1 = fma(sgn, a3.x, a0.y);
                    double v2 = fma(sgn, a2.y, a1.x);
                    double v3 = fma(sgn, a2.x, a1.y);
                    tp[h] = dl0*v0 + dl1*v1 + dl2*v2 + dl3*v3;
                }
                e2[m] = tp[0] + tp[1];
                o2[m] = tp[0] - tp[1];
            }
        } else {
            const double* base = ((c == 1) ? CbS : CrS) + q8 * 18;
            double u4[4];
            #pragma unroll
            for (int j2 = 0; j2 < 4; ++j2) {
                double2 a0 = *(const double2*)(base + j2 * 4);
                double2 a1 = *(const double2*)(base + j2 * 4 + 2);
                u4[j2] = dl01 * fma(sgn, a1.y, a0.x) + dl23 * fma(sgn, a1.x, a0.y);
            }
            e2[0] = e2[1] = u4[0] + u4[3];  o2[0] = o2[1] = u4[0] - u4[3];
            e2[2] = e2[3] = u4[1] + u4[2];  o2[2] = o2[3] = u4[1] - u4[2];
        }

        // zo[i] = Z[i][l] (exact small integers in f32)
        float zo[8];
        {
            const double2* dd2  = (const double2*)Dd;
            const double2* qrow = &qt[(c * 8 + l) * 9];
            #pragma unroll
            for (int i = 0; i < 8; ++i) {
                double2 dA = dd2[i * 2], dB = dd2[i * 2 + 1];
                double a64 = (i & 1)
                    ? dA.x*o2[0] + dA.y*o2[1] + dB.x*o2[2] + dB.y*o2[3]
                    : dA.x*e2[0] + dA.y*e2[1] + dB.x*e2[2] + dB.y*e2[3];
                double2 qe = qrow[i];
                zo[i] = (float)(rint(a64 * qe.x) * qe.y);
            }
        }

        // ---- col IDCT in registers: u[x] = sum_i zo[i] * D[i][x] ----
        float u[8];
        {
            float se0 = zo[0]*d0.x + zo[2]*d2.x + zo[4]*d4.x + zo[6]*d6.x;
            float se1 = zo[0]*d0.y + zo[2]*d2.y + zo[4]*d4.y + zo[6]*d6.y;
            float se2 = zo[0]*d0.z + zo[2]*d2.z + zo[4]*d4.z + zo[6]*d6.z;
            float se3 = zo[0]*d0.w + zo[2]*d2.w + zo[4]*d4.w + zo[6]*d6.w;
            float so0 = zo[1]*d1.x + zo[3]*d3.x + zo[5]*d5.x + zo[7]*d7.x;
            float so1 = zo[1]*d1.y + zo[3]*d3.y + zo[5]*d5.y + zo[7]*d7.y;
            float so2 = zo[1]*d1.z + zo[3]*d3.z + zo[5]*d5.z + zo[7]*d7.z;
            float so3 = zo[1]*d1.w + zo[3]*d3.w + zo[5]*d5.w + zo[7]*d7.w;
            u[0]=se0+so0; u[7]=se0-so0;
            u[1]=se1+so1; u[6]=se1-so1;
            u[2]=se2+so2; u[5]=se2-so2;
            u[3]=se3+so3; u[4]=se3-so3;
        }

        // ---- wave-local transpose: Vt[tile][x][l] = u[x] ----
        __builtin_amdgcn_wave_barrier();   // keep Ys fold reads before alias writes
        #pragma unroll
        for (int x = 0; x < 8; ++x) vtw[x * 8 + l] = u[x];
        __builtin_amdgcn_wave_barrier();   // DS ops of a wave execute in order
        float w2[8];
        {
            const float* vr = vtw + l * 8;   // this thread now owns pixel row x=l
            float4 wa = *(const float4*)(vr);
            float4 wb = *(const float4*)(vr + 4);
            w2[0]=wa.x; w2[1]=wa.y; w2[2]=wa.z; w2[3]=wa.w;
            w2[4]=wb.x; w2[5]=wb.y; w2[6]=wb.z; w2[7]=wb.w;
        }
        __builtin_amdgcn_wave_barrier();   // next channel overwrites Vt

        // ---- row IDCT: pix[x][y] = sum_k w2[k] * D[k][y] ----
        {
            float re0 = w2[0]*d0.x + w2[2]*d2.x + w2[4]*d4.x + w2[6]*d6.x;
            float re1 = w2[0]*d0.y + w2[2]*d2.y + w2[4]*d4.y + w2[6]*d6.y;
            float re2 = w2[0]*d0.z + w2[2]*d2.z + w2[4]*d4.z + w2[6]*d6.z;
            float re3 = w2[0]*d0.w + w2[2]*d2.w + w2[4]*d4.w + w2[6]*d6.w;
            float ro0 = w2[1]*d1.x + w2[3]*d3.x + w2[5]*d5.x + w2[7]*d7.x;
            float ro1 = w2[1]*d1.y + w2[3]*d3.y + w2[5]*d5.y + w2[7]*d7.y;
            float ro2 = w2[1]*d1.z + w2[3]*d3.z + w2[5]*d5.z + w2[7]*d7.z;
            float ro3 = w2[1]*d1.w + w2[3]*d3.w + w2[5]*d5.w + w2[7]*d7.w;
            acc[c][0]=re0+ro0; acc[c][7]=re0-ro0;
            acc[c][1]=re1+ro1; acc[c][6]=re1-ro1;
            acc[c][2]=re2+ro2; acc[c][5]=re2-ro2;
            acc[c][3]=re3+ro3; acc[c][4]=re3-ro3;
        }
    }

    // ---- RGB convert + row-major float4 stores (thread = pixel row l) ----
    {
        const int obase = ((b * 3) * IN_H + row0 + l) * IN_W + col0 + q8 * 8;
        float R4[8], G4[8], B4[8];
        #pragma unroll
        for (int y = 0; y < 8; ++y) {
            float im0 = acc[0][y] + 128.0f;
            float im1 = acc[1][y];
            float im2 = acc[2][y];
            float R  = fminf(fmaxf(im0 + 1.402f*im2, 0.0f), 255.0f);
            float G  = fminf(fmaxf(im0 - 0.344136286f*im1 - 0.714136286f*im2, 0.0f), 255.0f);
            float Bv = fminf(fmaxf(im0 + 1.772f*im1, 0.0f), 255.0f);
            R4[y] = rintf(R)  * (1.0f/255.0f);
            G4[y] = rintf(G)  * (1.0f/255.0f);
            B4[y] = rintf(Bv) * (1.0f/255.0f);
        }
        *(float4*)(out + obase)               = make_float4(R4[0],R4[1],R4[2],R4[3]);
        *(float4*)(out + obase + 4)           = make_float4(R4[4],R4[5],R4[6],R4[7]);
        *(float4*)(out + obase + chs)         = make_float4(G4[0],G4[1],G4[2],G4[3]);
        *(float4*)(out + obase + chs + 4)     = make_float4(G4[4],G4[5],G4[6],G4[7]);
        *(float4*)(out + obase + 2*chs)       = make_float4(B4[0],B4[1],B4[2],B4[3]);
        *(float4*)(out + obase + 2*chs + 4)   = make_float4(B4[4],B4[5],B4[6],B4[7]);
    }
}

extern "C" void kernel_launch(void* const* d_in, const int* in_sizes, int n_in,
                              void* d_out, int out_size, void* d_ws, size_t ws_size,
                              hipStream_t stream) {
    (void)in_sizes; (void)n_in; (void)out_size; (void)d_ws; (void)ws_size;
    const float* in  = (const float*)d_in[0];
    const float* qz  = (const float*)d_in[1];
    const float* dm  = (const float*)d_in[2];
    float* out = (float*)d_out;
    dim3 grid(4096), blk(256);
    hipLaunchKernelGGL(jpeg_kernel, grid, blk, 0, stream, in, qz, dm, out);
}

// Round 2
// 184.656 us; speedup vs baseline: 1.0142x; 1.0142x over previous
//
#include <hip/hip_runtime.h>

#define IN_H 512
#define IN_W 512

// One block = 8-row x 256-col strip (32 tiles), all 3 channels.
// Grid: 32 batches * 64 strip-rows * 2 strip-cols = 4096 blocks.
//
// LDS (30,976 B -> 5 blocks/CU):
//  Ys  @     0 : 32 tiles x 70 f64 (tile-major, pad 6)   = 17920
//      tile stride 560 B == 12 dwords mod 32 banks -> per-lane row reads/
//      writes and column b64 reads are bank-balanced (old stride 68 was 2x).
//      Vt aliased into bytes [272,544) of each tile's region (wave-private:
//      rows are dead after that wave's own c=0 column reads, which complete
//      in DS program order before the Vt writes).
//  CbS @ 17920 : 32 tiles x 18 f64 (4x4 subsampled +2)   =  4608
//  CrS @ 22528 : 32 tiles x 18 f64                       =  4608
//  qt  @ 27136 : 3 ch x 8 cols x 9 double2 {1/q, q}      =  3456
//  Dd  @ 30592 : 8x4 f64 half-DCT table                  =   256
//  Dh  @ 30848 : 8x4 f32 half-DCT table                  =   128
//
// R6: cooperative Y fold. Old: every thread re-read its whole tile (32x
// ds_read_b128, 8x redundant). New: thread l row-DCTs ONLY its own row
// (4x b128 read), writes the 8 freq outputs in-place over that row (4x b128
// write), wave_barrier, then reads its column (8x b64) for the column fold.
// Value-graph identical arithmetic (fma(+-1,x,y) == y+-x; same dot shapes,
// D rows taken as exact cvt_f64_f32 of the register f32 table).
// launch_bounds back to (256,2): R5's (256,5) forced VGPR 48 + ~12 B/thread
// scratch spills (WRITE_SIZE +12 MB) which ate the occupancy gain.

__global__ __launch_bounds__(256, 2) void jpeg_kernel(
    const float* __restrict__ in, const float* __restrict__ qz,
    const float* __restrict__ dmtx, float* __restrict__ out)
{
    __shared__ __align__(16) unsigned char smem[30976];
    double*  Ys  = (double*) (smem);
    double*  CbS = (double*) (smem + 17920);
    double*  CrS = (double*) (smem + 22528);
    double2* qt  = (double2*)(smem + 27136);
    double*  Dd  = (double*) (smem + 30592);
    float*   Dh  = (float*)  (smem + 30848);

    const int t   = threadIdx.x;
    const int blk = blockIdx.x;
    const int b   = blk >> 7;
    const int rr  = blk & 127;
    const int row0 = (rr >> 1) << 3;
    const int col0 = (rr & 1) << 8;
    const int chs = IN_H * IN_W;

    // ---- P0: tables ----
    if (t < 192) {
        const int c = t >> 6, i = (t >> 3) & 7, l = t & 7;
        double v  = (double)qz[t];
        double t1 = rint((rint(v * 255.0) * 50.0 + 50.0) / 100.0); // true div: .5 ties
        double q  = fmin(fmax(t1, 1.0), 255.0);
        qt[(c * 8 + l) * 9 + i] = make_double2(1.0 / q, q);
    }
    if (t < 32) {
        float dv = dmtx[(t >> 2) * 8 + (t & 3)];   // half table D[i][0..3]
        Dd[t] = (double)dv;
        Dh[t] = dv;
    }

    // ---- P1: load, RGB->YCbCr (f64), subsample, stage (tile-major) ----
    const int s  = t >> 6;   // row-pair 0..3
    const int c4 = t & 63;   // 4-col group
    {
        const int base = ((b * 3) * IN_H + row0 + 2 * s) * IN_W + col0 + 4 * c4;
        float4 ra = *(const float4*)(in + base);
        float4 rb = *(const float4*)(in + base + IN_W);
        float4 ga = *(const float4*)(in + base + chs);
        float4 gb = *(const float4*)(in + base + chs + IN_W);
        float4 ba = *(const float4*)(in + base + 2 * chs);
        float4 bb = *(const float4*)(in + base + 2 * chs + IN_W);

        float rA[2][4] = {{ra.x,ra.y,ra.z,ra.w},{rb.x,rb.y,rb.z,rb.w}};
        float gA[2][4] = {{ga.x,ga.y,ga.z,ga.w},{gb.x,gb.y,gb.z,gb.w}};
        float bA[2][4] = {{ba.x,ba.y,ba.z,ba.w},{bb.x,bb.y,bb.z,bb.w}};

        double yv[2][4], cbv[2][4], crv[2][4];
        #pragma unroll
        for (int p = 0; p < 2; ++p) {
            #pragma unroll
            for (int k = 0; k < 4; ++k) {
                double R = 255.0 * (double)rA[p][k];
                double G = 255.0 * (double)gA[p][k];
                double B = 255.0 * (double)bA[p][k];
                double y  =  0.299*R + 0.587*G + 0.114*B;
                double cb = -0.168735892*R - 0.331264108*G + 0.5*B + 128.0;
                double cr =  0.5*R - 0.418687589*G - 0.081312411*B + 128.0;
                yv[p][k]  = fmin(fmax(y , 0.0), 255.0) - 128.0;
                cbv[p][k] = fmin(fmax(cb, 0.0), 255.0);
                crv[p][k] = fmin(fmax(cr, 0.0), 255.0);
            }
        }
        const int tile = c4 >> 1, half = c4 & 1;
        #pragma unroll
        for (int p = 0; p < 2; ++p) {
            double* yp = &Ys[tile * 70 + (2*s + p) * 8 + 4 * half];
            *(double2*)(yp)     = make_double2(yv[p][0], yv[p][1]);
            *(double2*)(yp + 2) = make_double2(yv[p][2], yv[p][3]);
        }
        double m0 = (cbv[0][0]+cbv[0][1]+cbv[1][0]+cbv[1][1])*0.25 - 128.0;
        double m1 = (cbv[0][2]+cbv[0][3]+cbv[1][2]+cbv[1][3])*0.25 - 128.0;
        *(double2*)&CbS[tile * 18 + s * 4 + 2 * half] = make_double2(m0, m1);
        double n0 = (crv[0][0]+crv[0][1]+crv[1][0]+crv[1][1])*0.25 - 128.0;
        double n1 = (crv[0][2]+crv[0][3]+crv[1][2]+crv[1][3])*0.25 - 128.0;
        *(double2*)&CrS[tile * 18 + s * 4 + 2 * half] = make_double2(n0, n1);
    }
    __syncthreads();   // the ONLY block barrier

    // ---- per-thread constants ----
    const int q8 = t >> 3;     // tile 0..31
    const int l  = t & 7;      // row owned (Y row-DCT) / DCT column / pixel row
    double dl0, dl1, dl2, dl3;  // D[l][0..3] (chroma fold only)
    {
        double2 dA = *(const double2*)&Dd[l * 4];
        double2 dB = *(const double2*)&Dd[l * 4 + 2];
        dl0 = dA.x; dl1 = dA.y; dl2 = dB.x; dl3 = dB.y;
    }
    const double sgn  = (l & 1) ? -1.0 : 1.0;
    const double dl01 = dl0 + dl1, dl23 = dl2 + dl3;
    // f32 half-table in registers (G-dots via exact cvt, both IDCT folds)
    const float4* dh4p = (const float4*)Dh;
    float4 d0 = dh4p[0], d1 = dh4p[1], d2 = dh4p[2], d3 = dh4p[3];
    float4 d4 = dh4p[4], d5 = dh4p[5], d6 = dh4p[6], d7 = dh4p[7];

    float acc[3][8];
    // wave-private tile patch, aliased into bytes [272,544) of this tile's
    // Ys region (dead after this wave's own c=0 column reads)
    float* vtw = (float*)(smem + q8 * 560 + 272);

    #pragma unroll
    for (int c = 0; c < 3; ++c) {
        // ---- F: row DCT -> in-place transpose -> col fold -> quant ----
        double e2[4], o2[4];
        if (c == 0) {
            // pass 1: thread l row-DCTs its OWN row l, writes back in place
            double* rowp = &Ys[q8 * 70 + l * 8];
            {
                double2 a0 = *(const double2*)(rowp);
                double2 a1 = *(const double2*)(rowp + 2);
                double2 a2 = *(const double2*)(rowp + 4);
                double2 a3 = *(const double2*)(rowp + 6);
                double ev0 = a0.x + a3.y, ov0 = a0.x - a3.y;
                double ev1 = a0.y + a3.x, ov1 = a0.y - a3.x;
                double ev2 = a1.x + a2.y, ov2 = a1.x - a2.y;
                double ev3 = a1.y + a2.x, ov3 = a1.y - a2.x;
                double g0v = (double)d0.x*ev0 + (double)d0.y*ev1 + (double)d0.z*ev2 + (double)d0.w*ev3;
                double g1v = (double)d1.x*ov0 + (double)d1.y*ov1 + (double)d1.z*ov2 + (double)d1.w*ov3;
                double g2v = (double)d2.x*ev0 + (double)d2.y*ev1 + (double)d2.z*ev2 + (double)d2.w*ev3;
                double g3v = (double)d3.x*ov0 + (double)d3.y*ov1 + (double)d3.z*ov2 + (double)d3.w*ov3;
                double g4v = (double)d4.x*ev0 + (double)d4.y*ev1 + (double)d4.z*ev2 + (double)d4.w*ev3;
                double g5v = (double)d5.x*ov0 + (double)d5.y*ov1 + (double)d5.z*ov2 + (double)d5.w*ov3;
                double g6v = (double)d6.x*ev0 + (double)d6.y*ev1 + (double)d6.z*ev2 + (double)d6.w*ev3;
                double g7v = (double)d7.x*ov0 + (double)d7.y*ov1 + (double)d7.z*ov2 + (double)d7.w*ov3;
                *(double2*)(rowp)     = make_double2(g0v, g1v);
                *(double2*)(rowp + 2) = make_double2(g2v, g3v);
                *(double2*)(rowp + 4) = make_double2(g4v, g5v);
                *(double2*)(rowp + 6) = make_double2(g6v, g7v);
            }
            __builtin_amdgcn_wave_barrier();   // all 8 G-rows of the tile landed
            // pass 2: thread l reads column l, folds over rows
            const double* tb = &Ys[q8 * 70 + l];
            #pragma unroll
            for (int m = 0; m < 4; ++m) {
                double gm = tb[m * 8];
                double g7 = tb[(7 - m) * 8];
                e2[m] = gm + g7;
                o2[m] = gm - g7;
            }
        } else {
            const double* base = ((c == 1) ? CbS : CrS) + q8 * 18;
            double u4[4];
            #pragma unroll
            for (int j2 = 0; j2 < 4; ++j2) {
                double2 a0 = *(const double2*)(base + j2 * 4);
                double2 a1 = *(const double2*)(base + j2 * 4 + 2);
                u4[j2] = dl01 * fma(sgn, a1.y, a0.x) + dl23 * fma(sgn, a1.x, a0.y);
            }
            e2[0] = e2[1] = u4[0] + u4[3];  o2[0] = o2[1] = u4[0] - u4[3];
            e2[2] = e2[3] = u4[1] + u4[2];  o2[2] = o2[3] = u4[1] - u4[2];
        }

        // zo[i] = Z[i][l] (exact small integers in f32)
        float zo[8];
        {
            const double2* dd2  = (const double2*)Dd;
            const double2* qrow = &qt[(c * 8 + l) * 9];
            #pragma unroll
            for (int i = 0; i < 8; ++i) {
                double2 dA = dd2[i * 2], dB = dd2[i * 2 + 1];
                double a64 = (i & 1)
                    ? dA.x*o2[0] + dA.y*o2[1] + dB.x*o2[2] + dB.y*o2[3]
                    : dA.x*e2[0] + dA.y*e2[1] + dB.x*e2[2] + dB.y*e2[3];
                double2 qe = qrow[i];
                zo[i] = (float)(rint(a64 * qe.x) * qe.y);
            }
        }

        // ---- col IDCT in registers: u[x] = sum_i zo[i] * D[i][x] ----
        float u[8];
        {
            float se0 = zo[0]*d0.x + zo[2]*d2.x + zo[4]*d4.x + zo[6]*d6.x;
            float se1 = zo[0]*d0.y + zo[2]*d2.y + zo[4]*d4.y + zo[6]*d6.y;
            float se2 = zo[0]*d0.z + zo[2]*d2.z + zo[4]*d4.z + zo[6]*d6.z;
            float se3 = zo[0]*d0.w + zo[2]*d2.w + zo[4]*d4.w + zo[6]*d6.w;
            float so0 = zo[1]*d1.x + zo[3]*d3.x + zo[5]*d5.x + zo[7]*d7.x;
            float so1 = zo[1]*d1.y + zo[3]*d3.y + zo[5]*d5.y + zo[7]*d7.y;
            float so2 = zo[1]*d1.z + zo[3]*d3.z + zo[5]*d5.z + zo[7]*d7.z;
            float so3 = zo[1]*d1.w + zo[3]*d3.w + zo[5]*d5.w + zo[7]*d7.w;
            u[0]=se0+so0; u[7]=se0-so0;
            u[1]=se1+so1; u[6]=se1-so1;
            u[2]=se2+so2; u[5]=se2-so2;
            u[3]=se3+so3; u[4]=se3-so3;
        }

        // ---- wave-local transpose: Vt[tile][x][l] = u[x] ----
        __builtin_amdgcn_wave_barrier();   // keep Ys column reads before alias writes
        #pragma unroll
        for (int x = 0; x < 8; ++x) vtw[x * 8 + l] = u[x];
        __builtin_amdgcn_wave_barrier();   // DS ops of a wave execute in order
        float w2[8];
        {
            const float* vr = vtw + l * 8;   // this thread now owns pixel row x=l
            float4 wa = *(const float4*)(vr);
            float4 wb = *(const float4*)(vr + 4);
            w2[0]=wa.x; w2[1]=wa.y; w2[2]=wa.z; w2[3]=wa.w;
            w2[4]=wb.x; w2[5]=wb.y; w2[6]=wb.z; w2[7]=wb.w;
        }
        __builtin_amdgcn_wave_barrier();   // next channel overwrites Vt

        // ---- row IDCT: pix[x][y] = sum_k w2[k] * D[k][y] ----
        {
            float re0 = w2[0]*d0.x + w2[2]*d2.x + w2[4]*d4.x + w2[6]*d6.x;
            float re1 = w2[0]*d0.y + w2[2]*d2.y + w2[4]*d4.y + w2[6]*d6.y;
            float re2 = w2[0]*d0.z + w2[2]*d2.z + w2[4]*d4.z + w2[6]*d6.z;
            float re3 = w2[0]*d0.w + w2[2]*d2.w + w2[4]*d4.w + w2[6]*d6.w;
            float ro0 = w2[1]*d1.x + w2[3]*d3.x + w2[5]*d5.x + w2[7]*d7.x;
            float ro1 = w2[1]*d1.y + w2[3]*d3.y + w2[5]*d5.y + w2[7]*d7.y;
            float ro2 = w2[1]*d1.z + w2[3]*d3.z + w2[5]*d5.z + w2[7]*d7.z;
            float ro3 = w2[1]*d1.w + w2[3]*d3.w + w2[5]*d5.w + w2[7]*d7.w;
            acc[c][0]=re0+ro0; acc[c][7]=re0-ro0;
            acc[c][1]=re1+ro1; acc[c][6]=re1-ro1;
            acc[c][2]=re2+ro2; acc[c][5]=re2-ro2;
            acc[c][3]=re3+ro3; acc[c][4]=re3-ro3;
        }
    }

    // ---- RGB convert + row-major float4 stores (thread = pixel row l) ----
    {
        const int obase = ((b * 3) * IN_H + row0 + l) * IN_W + col0 + q8 * 8;
        float R4[8], G4[8], B4[8];
        #pragma unroll
        for (int y = 0; y < 8; ++y) {
            float im0 = acc[0][y] + 128.0f;
            float im1 = acc[1][y];
            float im2 = acc[2][y];
            float R  = fminf(fmaxf(im0 + 1.402f*im2, 0.0f), 255.0f);
            float G  = fminf(fmaxf(im0 - 0.344136286f*im1 - 0.714136286f*im2, 0.0f), 255.0f);
            float Bv = fminf(fmaxf(im0 + 1.772f*im1, 0.0f), 255.0f);
            R4[y] = rintf(R)  * (1.0f/255.0f);
            G4[y] = rintf(G)  * (1.0f/255.0f);
            B4[y] = rintf(Bv) * (1.0f/255.0f);
        }
        *(float4*)(out + obase)               = make_float4(R4[0],R4[1],R4[2],R4[3]);
        *(float4*)(out + obase + 4)           = make_float4(R4[4],R4[5],R4[6],R4[7]);
        *(float4*)(out + obase + chs)         = make_float4(G4[0],G4[1],G4[2],G4[3]);
        *(float4*)(out + obase + chs + 4)     = make_float4(G4[4],G4[5],G4[6],G4[7]);
        *(float4*)(out + obase + 2*chs)       = make_float4(B4[0],B4[1],B4[2],B4[3]);
        *(float4*)(out + obase + 2*chs + 4)   = make_float4(B4[4],B4[5],B4[6],B4[7]);
    }
}

extern "C" void kernel_launch(void* const* d_in, const int* in_sizes, int n_in,
                              void* d_out, int out_size, void* d_ws, size_t ws_size,
                              hipStream_t stream) {
    (void)in_sizes; (void)n_in; (void)out_size; (void)d_ws; (void)ws_size;
    const float* in  = (const float*)d_in[0];
    const float* qz  = (const float*)d_in[1];
    const float* dm  = (const float*)d_in[2];
    float* out = (float*)d_out;
    dim3 grid(4096), blk(256);
    hipLaunchKernelGGL(jpeg_kernel, grid, blk, 0, stream, in, qz, dm, out);
}

// Round 3
// 181.511 us; speedup vs baseline: 1.0318x; 1.0173x over previous
//
#include <hip/hip_runtime.h>

#define IN_H 512
#define IN_W 512

// One block = 8-row x 256-col strip (32 tiles), all 3 channels.
// Grid: 32 batches * 64 strip-rows * 2 strip-cols = 4096 blocks.
//
// LDS (30,464 B -> 5 blocks/CU):
//  Ys  @     0 : 32 tiles x 68 f64 (tile-major, pad 4)   = 17408
//      Vt double-buffered in each tile's own region (dead after that
//      wave's c=0 fold reads): A at +0 (256 B), B at +288 (256 B).
//  CbS @ 17408 : 32 tiles x 18 f64 (4x4 subsampled +2)   =  4608
//  CrS @ 22016 : 32 tiles x 18 f64                       =  4608
//  qt  @ 26624 : 3 ch x 8 cols x 9 double2 {1/q, q}      =  3456
//  Dd  @ 30080 : 8x4 f64 half-DCT table                  =   256
//  Dh  @ 30336 : 8x4 f32 half-DCT table                  =   128
//
// R7 (from R4's verified broadcast fold; R6's cooperative fold reverted --
// it raised bank conflicts 2x and lengthened the DS chain):
//  1. Wave-private staging: wave w stages tiles 8w..8w+7 (lane = tile.half.
//     rowpair), so fold reads only own-wave DS writes (in-order pipe).
//     __syncthreads moved BEFORE pixel work -- it now only covers the tiny
//     qt/Dd/Dh table build, not the 6 global-load latencies.
//  2. Channel fusion: all 3 folds (e2/o2) first -> one i-loop makes
//     zo[3][8], sharing Dd broadcast reads across channels (48->16 b128);
//     then 3 epilogues with A/B Vt buffers (no inter-channel serialization).
//  Arithmetic is expression-for-expression identical to R4 (absmax must
//  stay 0.01367188).

__global__ __launch_bounds__(256, 2) void jpeg_kernel(
    const float* __restrict__ in, const float* __restrict__ qz,
    const float* __restrict__ dmtx, float* __restrict__ out)
{
    __shared__ __align__(16) unsigned char smem[30464];
    double*  Ys  = (double*) (smem);
    double*  CbS = (double*) (smem + 17408);
    double*  CrS = (double*) (smem + 22016);
    double2* qt  = (double2*)(smem + 26624);
    double*  Dd  = (double*) (smem + 30080);
    float*   Dh  = (float*)  (smem + 30336);

    const int t   = threadIdx.x;
    const int blk = blockIdx.x;
    const int b   = blk >> 7;
    const int rr  = blk & 127;
    const int row0 = (rr >> 1) << 3;
    const int col0 = (rr & 1) << 8;
    const int chs = IN_H * IN_W;

    // ---- wave-private staging mapping: tile = t>>3 (same as fold's q8!),
    //      half = (t>>2)&1, rowpair s = t&3 ----
    const int tile = t >> 3;          // 0..31, wave w owns 8w..8w+7
    const int h4   = (t >> 2) & 1;    // 4-col half
    const int s    = t & 3;           // row-pair

    // ---- issue pixel loads FIRST (before the table barrier) ----
    const int base = ((b * 3) * IN_H + row0 + 2 * s) * IN_W + col0 + tile * 8 + 4 * h4;
    float4 ra = *(const float4*)(in + base);
    float4 rb = *(const float4*)(in + base + IN_W);
    float4 ga = *(const float4*)(in + base + chs);
    float4 gb = *(const float4*)(in + base + chs + IN_W);
    float4 ba = *(const float4*)(in + base + 2 * chs);
    float4 bb = *(const float4*)(in + base + 2 * chs + IN_W);

    // ---- P0: tables (the ONLY cross-wave data) ----
    if (t < 192) {
        const int c = t >> 6, i = (t >> 3) & 7, l = t & 7;
        double v  = (double)qz[t];
        double t1 = rint((rint(v * 255.0) * 50.0 + 50.0) / 100.0); // true div: .5 ties
        double q  = fmin(fmax(t1, 1.0), 255.0);
        qt[(c * 8 + l) * 9 + i] = make_double2(1.0 / q, q);
    }
    if (t < 32) {
        float dv = dmtx[(t >> 2) * 8 + (t & 3)];   // half table D[i][0..3]
        Dd[t] = (double)dv;
        Dh[t] = dv;
    }
    __syncthreads();   // tables only -- NOT gated on pixel loads

    // ---- P1: RGB->YCbCr (f64), subsample, stage own wave's tiles ----
    {
        float rA[2][4] = {{ra.x,ra.y,ra.z,ra.w},{rb.x,rb.y,rb.z,rb.w}};
        float gA[2][4] = {{ga.x,ga.y,ga.z,ga.w},{gb.x,gb.y,gb.z,gb.w}};
        float bA[2][4] = {{ba.x,ba.y,ba.z,ba.w},{bb.x,bb.y,bb.z,bb.w}};

        double yv[2][4], cbv[2][4], crv[2][4];
        #pragma unroll
        for (int p = 0; p < 2; ++p) {
            #pragma unroll
            for (int k = 0; k < 4; ++k) {
                double R = 255.0 * (double)rA[p][k];
                double G = 255.0 * (double)gA[p][k];
                double B = 255.0 * (double)bA[p][k];
                double y  =  0.299*R + 0.587*G + 0.114*B;
                double cb = -0.168735892*R - 0.331264108*G + 0.5*B + 128.0;
                double cr =  0.5*R - 0.418687589*G - 0.081312411*B + 128.0;
                yv[p][k]  = fmin(fmax(y , 0.0), 255.0) - 128.0;
                cbv[p][k] = fmin(fmax(cb, 0.0), 255.0);
                crv[p][k] = fmin(fmax(cr, 0.0), 255.0);
            }
        }
        #pragma unroll
        for (int p = 0; p < 2; ++p) {
            double* yp = &Ys[tile * 68 + (2*s + p) * 8 + 4 * h4];
            *(double2*)(yp)     = make_double2(yv[p][0], yv[p][1]);
            *(double2*)(yp + 2) = make_double2(yv[p][2], yv[p][3]);
        }
        double m0 = (cbv[0][0]+cbv[0][1]+cbv[1][0]+cbv[1][1])*0.25 - 128.0;
        double m1 = (cbv[0][2]+cbv[0][3]+cbv[1][2]+cbv[1][3])*0.25 - 128.0;
        *(double2*)&CbS[tile * 18 + s * 4 + 2 * h4] = make_double2(m0, m1);
        double n0 = (crv[0][0]+crv[0][1]+crv[1][0]+crv[1][1])*0.25 - 128.0;
        double n1 = (crv[0][2]+crv[0][3]+crv[1][2]+crv[1][3])*0.25 - 128.0;
        *(double2*)&CrS[tile * 18 + s * 4 + 2 * h4] = make_double2(n0, n1);
    }
    __builtin_amdgcn_wave_barrier();   // own-wave DS writes before fold reads

    // ---- per-thread constants ----
    const int q8 = t >> 3;     // tile (== staging tile)
    const int l  = t & 7;      // DCT column (F) / pixel row (I)
    double dl0, dl1, dl2, dl3;  // D[l][0..3]
    {
        double2 dA = *(const double2*)&Dd[l * 4];
        double2 dB = *(const double2*)&Dd[l * 4 + 2];
        dl0 = dA.x; dl1 = dA.y; dl2 = dB.x; dl3 = dB.y;
    }
    const double sgn  = (l & 1) ? -1.0 : 1.0;
    const double dl01 = dl0 + dl1, dl23 = dl2 + dl3;

    // ---- folds for ALL THREE channels (independent chains) ----
    double e20[4], o20[4];
    {
        const double* basep = &Ys[q8 * 68];
        #pragma unroll
        for (int m = 0; m < 4; ++m) {
            double tp[2];
            #pragma unroll
            for (int hh = 0; hh < 2; ++hh) {
                const double* p = basep + (hh ? (7 - m) : m) * 8;
                double2 a0 = *(const double2*)(p);
                double2 a1 = *(const double2*)(p + 2);
                double2 a2 = *(const double2*)(p + 4);
                double2 a3 = *(const double2*)(p + 6);
                double v0 = fma(sgn, a3.y, a0.x);
                double v1 = fma(sgn, a3.x, a0.y);
                double v2 = fma(sgn, a2.y, a1.x);
                double v3 = fma(sgn, a2.x, a1.y);
                tp[hh] = dl0*v0 + dl1*v1 + dl2*v2 + dl3*v3;
            }
            e20[m] = tp[0] + tp[1];
            o20[m] = tp[0] - tp[1];
        }
    }
    double e21[4], o21[4], e22[4], o22[4];
    #pragma unroll
    for (int cc = 0; cc < 2; ++cc) {
        const double* basep = (cc == 0 ? CbS : CrS) + q8 * 18;
        double u4[4];
        #pragma unroll
        for (int j2 = 0; j2 < 4; ++j2) {
            double2 a0 = *(const double2*)(basep + j2 * 4);
            double2 a1 = *(const double2*)(basep + j2 * 4 + 2);
            u4[j2] = dl01 * fma(sgn, a1.y, a0.x) + dl23 * fma(sgn, a1.x, a0.y);
        }
        double ea = u4[0] + u4[3], oa = u4[0] - u4[3];
        double eb = u4[1] + u4[2], ob = u4[1] - u4[2];
        if (cc == 0) { e21[0]=e21[1]=ea; o21[0]=o21[1]=oa; e21[2]=e21[3]=eb; o21[2]=o21[3]=ob; }
        else         { e22[0]=e22[1]=ea; o22[0]=o22[1]=oa; e22[2]=e22[3]=eb; o22[2]=o22[3]=ob; }
    }

    // ---- fused quant: zo[c][i] = Z[i][l], Dd reads shared across channels ----
    float zo[3][8];
    {
        const double2* dd2 = (const double2*)Dd;
        #pragma unroll
        for (int i = 0; i < 8; ++i) {
            double2 dA = dd2[i * 2], dB = dd2[i * 2 + 1];
            #define ZQ(C, E, O) { \
                double a64 = (i & 1) \
                    ? dA.x*O[0] + dA.y*O[1] + dB.x*O[2] + dB.y*O[3] \
                    : dA.x*E[0] + dA.y*E[1] + dB.x*E[2] + dB.y*E[3]; \
                double2 qe = qt[(C * 8 + l) * 9 + i]; \
                zo[C][i] = (float)(rint(a64 * qe.x) * qe.y); }
            ZQ(0, e20, o20)
            ZQ(1, e21, o21)
            ZQ(2, e22, o22)
            #undef ZQ
        }
    }

    // f32 half-table in registers (loaded AFTER the f64 phase to cap pressure)
    const float4* dh4p = (const float4*)Dh;
    float4 d0 = dh4p[0], d1 = dh4p[1], d2 = dh4p[2], d3 = dh4p[3];
    float4 d4 = dh4p[4], d5 = dh4p[5], d6 = dh4p[6], d7 = dh4p[7];

    float acc[3][8];
    // Vt double-buffer in this tile's own (dead) Ys region
    float* vtwA = (float*)(smem + q8 * 544);
    float* vtwB = (float*)(smem + q8 * 544 + 288);

    #define EPI(C, VT) { \
        float se0 = zo[C][0]*d0.x + zo[C][2]*d2.x + zo[C][4]*d4.x + zo[C][6]*d6.x; \
        float se1 = zo[C][0]*d0.y + zo[C][2]*d2.y + zo[C][4]*d4.y + zo[C][6]*d6.y; \
        float se2 = zo[C][0]*d0.z + zo[C][2]*d2.z + zo[C][4]*d4.z + zo[C][6]*d6.z; \
        float se3 = zo[C][0]*d0.w + zo[C][2]*d2.w + zo[C][4]*d4.w + zo[C][6]*d6.w; \
        float so0 = zo[C][1]*d1.x + zo[C][3]*d3.x + zo[C][5]*d5.x + zo[C][7]*d7.x; \
        float so1 = zo[C][1]*d1.y + zo[C][3]*d3.y + zo[C][5]*d5.y + zo[C][7]*d7.y; \
        float so2 = zo[C][1]*d1.z + zo[C][3]*d3.z + zo[C][5]*d5.z + zo[C][7]*d7.z; \
        float so3 = zo[C][1]*d1.w + zo[C][3]*d3.w + zo[C][5]*d5.w + zo[C][7]*d7.w; \
        float u0 = se0+so0, u7 = se0-so0; \
        float u1 = se1+so1, u6 = se1-so1; \
        float u2 = se2+so2, u5 = se2-so2; \
        float u3 = se3+so3, u4v = se3-so3; \
        __builtin_amdgcn_wave_barrier(); \
        VT[0*8+l]=u0; VT[1*8+l]=u1; VT[2*8+l]=u2; VT[3*8+l]=u3; \
        VT[4*8+l]=u4v; VT[5*8+l]=u5; VT[6*8+l]=u6; VT[7*8+l]=u7; \
        __builtin_amdgcn_wave_barrier(); \
        float4 wa = *(const float4*)(VT + l * 8); \
        float4 wb = *(const float4*)(VT + l * 8 + 4); \
        __builtin_amdgcn_wave_barrier(); \
        float re0 = wa.x*d0.x + wa.z*d2.x + wb.x*d4.x + wb.z*d6.x; \
        float re1 = wa.x*d0.y + wa.z*d2.y + wb.x*d4.y + wb.z*d6.y; \
        float re2 = wa.x*d0.z + wa.z*d2.z + wb.x*d4.z + wb.z*d6.z; \
        float re3 = wa.x*d0.w + wa.z*d2.w + wb.x*d4.w + wb.z*d6.w; \
        float ro0 = wa.y*d1.x + wa.w*d3.x + wb.y*d5.x + wb.w*d7.x; \
        float ro1 = wa.y*d1.y + wa.w*d3.y + wb.y*d5.y + wb.w*d7.y; \
        float ro2 = wa.y*d1.z + wa.w*d3.z + wb.y*d5.z + wb.w*d7.z; \
        float ro3 = wa.y*d1.w + wa.w*d3.w + wb.y*d5.w + wb.w*d7.w; \
        acc[C][0]=re0+ro0; acc[C][7]=re0-ro0; \
        acc[C][1]=re1+ro1; acc[C][6]=re1-ro1; \
        acc[C][2]=re2+ro2; acc[C][5]=re2-ro2; \
        acc[C][3]=re3+ro3; acc[C][4]=re3-ro3; }

    EPI(0, vtwA)    // A: Ys bytes [0,256) of own tile -- dead after c=0 fold
    EPI(1, vtwB)    // B: bytes [288,544) -- no dependency on A
    EPI(2, vtwA)    // A reuse: c=0's reads long retired (in-order DS)
    #undef EPI

    // ---- RGB convert + row-major float4 stores (thread = pixel row l) ----
    {
        const int obase = ((b * 3) * IN_H + row0 + l) * IN_W + col0 + q8 * 8;
        float R4[8], G4[8], B4[8];
        #pragma unroll
        for (int y = 0; y < 8; ++y) {
            float im0 = acc[0][y] + 128.0f;
            float im1 = acc[1][y];
            float im2 = acc[2][y];
            float R  = fminf(fmaxf(im0 + 1.402f*im2, 0.0f), 255.0f);
            float G  = fminf(fmaxf(im0 - 0.344136286f*im1 - 0.714136286f*im2, 0.0f), 255.0f);
            float Bv = fminf(fmaxf(im0 + 1.772f*im1, 0.0f), 255.0f);
            R4[y] = rintf(R)  * (1.0f/255.0f);
            G4[y] = rintf(G)  * (1.0f/255.0f);
            B4[y] = rintf(Bv) * (1.0f/255.0f);
        }
        *(float4*)(out + obase)               = make_float4(R4[0],R4[1],R4[2],R4[3]);
        *(float4*)(out + obase + 4)           = make_float4(R4[4],R4[5],R4[6],R4[7]);
        *(float4*)(out + obase + chs)         = make_float4(G4[0],G4[1],G4[2],G4[3]);
        *(float4*)(out + obase + chs + 4)     = make_float4(G4[4],G4[5],G4[6],G4[7]);
        *(float4*)(out + obase + 2*chs)       = make_float4(B4[0],B4[1],B4[2],B4[3]);
        *(float4*)(out + obase + 2*chs + 4)   = make_float4(B4[4],B4[5],B4[6],B4[7]);
    }
}

extern "C" void kernel_launch(void* const* d_in, const int* in_sizes, int n_in,
                              void* d_out, int out_size, void* d_ws, size_t ws_size,
                              hipStream_t stream) {
    (void)in_sizes; (void)n_in; (void)out_size; (void)d_ws; (void)ws_size;
    const float* in  = (const float*)d_in[0];
    const float* qz  = (const float*)d_in[1];
    const float* dm  = (const float*)d_in[2];
    float* out = (float*)d_out;
    dim3 grid(4096), blk(256);
    hipLaunchKernelGGL(jpeg_kernel, grid, blk, 0, stream, in, qz, dm, out);
}